// Round 1
// baseline (715.484 us; speedup 1.0000x reference)
//
#include <hip/hip_runtime.h>
#include <hip/hip_bf16.h>
#include <math.h>

#define NB 4
#define NN 1024
#define DIMD 512
#define NH 8
#define DHD 64
#define INNERD 512
#define SCALE 0.125f
#define TEMPP 0.1f
#define KREG 0.3f
#define LNEG -23.025850929940457f

typedef __attribute__((ext_vector_type(8))) short bf16x8;
typedef __attribute__((ext_vector_type(4))) short bf16x4;
typedef __attribute__((ext_vector_type(4))) float f32x4;

static __device__ __forceinline__ short f2bf(float f) {
  unsigned u = __float_as_uint(f);
  u += 0x7fffu + ((u >> 16) & 1u);
  return (short)(u >> 16);
}

static __device__ __forceinline__ float wave_max(float v) {
#pragma unroll
  for (int o = 1; o < 64; o <<= 1) v = fmaxf(v, __shfl_xor(v, o, 64));
  return v;
}
static __device__ __forceinline__ float wave_sum(float v) {
#pragma unroll
  for (int o = 1; o < 64; o <<= 1) v += __shfl_xor(v, o, 64);
  return v;
}

// ---------------------------------------------------------------------------
// K1: fused QKV projection. out = x @ W.T + b, written bf16 in (B,H,N,DH).
// Also computes q_norm / k_norm from the f32 accumulators (post-bias).
// grid (64, 24): x = row-tile (64 rows), y = 24 col-tiles of stacked [Wq;Wk;Wv]
// ---------------------------------------------------------------------------
__global__ __launch_bounds__(256) void k_qkv(
    const float* __restrict__ x,
    const float* __restrict__ Wq, const float* __restrict__ bq,
    const float* __restrict__ Wk, const float* __restrict__ bk,
    const float* __restrict__ Wv, const float* __restrict__ bv,
    short* __restrict__ Qb, short* __restrict__ Kb, short* __restrict__ Vb,
    float* __restrict__ qn, float* __restrict__ kn) {
  __shared__ __align__(16) short As[64][40];  // 40 = 32 + 8 pad (80B = 5*16B)
  __shared__ __align__(16) short Bs[64][40];
  const int tid = threadIdx.x;
  const int lane = tid & 63;
  const int wv = tid >> 6;
  const int m0 = blockIdx.x * 64;
  const int oc = blockIdx.y;
  const int which = oc >> 3;  // 0=q 1=k 2=v
  const int h = oc & 7;
  const float* W = (which == 0) ? Wq : (which == 1) ? Wk : Wv;
  const float* bias = (which == 0) ? bq : (which == 1) ? bk : bv;
  short* Out = (which == 0) ? Qb : (which == 1) ? Kb : Vb;
  const int o0 = h * 64;

  const f32x4 zero4 = {0.f, 0.f, 0.f, 0.f};
  f32x4 acc[4] = {zero4, zero4, zero4, zero4};

  const int sr = tid >> 3;       // staging row (t=0), +32 for t=1
  const int sc = (tid & 7) * 4;  // staging col

  for (int ks = 0; ks < 16; ++ks) {
    const int k0 = ks * 32;
    __syncthreads();
#pragma unroll
    for (int t = 0; t < 2; ++t) {
      const int r = sr + t * 32;
      const f32x4 va = *reinterpret_cast<const f32x4*>(&x[(m0 + r) * DIMD + k0 + sc]);
      const f32x4 vb = *reinterpret_cast<const f32x4*>(&W[(o0 + r) * DIMD + k0 + sc]);
      bf16x4 pa, pb;
#pragma unroll
      for (int i2 = 0; i2 < 4; ++i2) { pa[i2] = f2bf(va[i2]); pb[i2] = f2bf(vb[i2]); }
      *reinterpret_cast<bf16x4*>(&As[r][sc]) = pa;
      *reinterpret_cast<bf16x4*>(&Bs[r][sc]) = pb;
    }
    __syncthreads();
    const int kk = (lane >> 4) * 8;
    const bf16x8 a = *reinterpret_cast<const bf16x8*>(&As[wv * 16 + (lane & 15)][kk]);
#pragma unroll
    for (int n = 0; n < 4; ++n) {
      const bf16x8 b = *reinterpret_cast<const bf16x8*>(&Bs[n * 16 + (lane & 15)][kk]);
      acc[n] = __builtin_amdgcn_mfma_f32_16x16x32_bf16(a, b, acc[n], 0, 0, 0);
    }
  }

  const int colb = lane & 15;
  const int rbase = m0 + wv * 16 + ((lane >> 4) << 2);
  const int bidx = m0 >> 10;
  const int hb = (bidx * NH + h) << 10;  // (b*H + h)*N
  float p2[4] = {0.f, 0.f, 0.f, 0.f};
#pragma unroll
  for (int n = 0; n < 4; ++n) {
    const float bval = bias[o0 + n * 16 + colb];
#pragma unroll
    for (int i = 0; i < 4; ++i) {
      const float val = acc[n][i] + bval;
      p2[i] += val * val;
      const int m = rbase + i;
      Out[(long)(hb + (m & (NN - 1))) * DHD + n * 16 + colb] = f2bf(val);
    }
  }
  if (which < 2) {
    float* norm = (which == 0) ? qn : kn;
#pragma unroll
    for (int off = 1; off < 16; off <<= 1) {
#pragma unroll
      for (int i = 0; i < 4; ++i) p2[i] += __shfl_xor(p2[i], off, 64);
    }
    if (colb == 0) {
#pragma unroll
      for (int i = 0; i < 4; ++i) {
        const int m = rbase + i;
        norm[hb + (m & (NN - 1))] = sqrtf(p2[i]);
      }
    }
  }
}

// ---------------------------------------------------------------------------
// K1.5: transpose V: (bh, j, d) -> (bh, d, j) so PV's B-fragment is contiguous
// grid (16, 32): x = 64-wide j tile, y = bh
// ---------------------------------------------------------------------------
__global__ __launch_bounds__(256) void k_vtrans(const short* __restrict__ Vb,
                                                short* __restrict__ VbT) {
  __shared__ __align__(16) short T[64][72];
  const int tid = threadIdx.x;
  const int bh = blockIdx.y;
  const int j0 = blockIdx.x * 64;
#pragma unroll
  for (int t = 0; t < 2; ++t) {
    const int idx = tid + 256 * t;
    const int r = idx >> 3, c8 = (idx & 7) * 8;
    *reinterpret_cast<bf16x8*>(&T[r][c8]) =
        *reinterpret_cast<const bf16x8*>(&Vb[(long)((bh << 10) + j0 + r) * DHD + c8]);
  }
  __syncthreads();
  const int d = tid & 63;
  const int cg = tid >> 6;
#pragma unroll
  for (int t = 0; t < 2; ++t) {
    const int ch = cg * 2 + t;  // 0..7
    bf16x8 v;
#pragma unroll
    for (int jj = 0; jj < 8; ++jj) v[jj] = T[ch * 8 + jj][d];
    *reinterpret_cast<bf16x8*>(&VbT[((long)(bh * DHD + d) << 10) + j0 + ch * 8]) = v;
  }
}

// ---------------------------------------------------------------------------
// K2: regular_b sum: sum |eye - mask| over everything -> accum[1]
// ---------------------------------------------------------------------------
__global__ __launch_bounds__(256) void k_regular(const float* __restrict__ mask,
                                                 float* __restrict__ accum) {
  const int tid = threadIdx.x;
  float s = 0.f;
  const int total4 = (NB * NN * NN) / 4;
  for (int idx = blockIdx.x * 256 + tid; idx < total4; idx += gridDim.x * 256) {
    const f32x4 mv = *reinterpret_cast<const f32x4*>(&mask[(long)idx * 4]);
    const int flat = idx * 4;
    const int i = (flat >> 10) & (NN - 1);
    const int j = flat & (NN - 1);
#pragma unroll
    for (int c = 0; c < 4; ++c) {
      const float e = (j + c == i) ? 1.0f : 0.0f;
      s += fabsf(e - mv[c]);
    }
  }
  s = wave_sum(s);
  __shared__ float red[4];
  if ((tid & 63) == 0) red[tid >> 6] = s;
  __syncthreads();
  if (tid == 0) atomicAdd(accum + 1, red[0] + red[1] + red[2] + red[3]);
}

// ---------------------------------------------------------------------------
// K3a: raw scores = q @ k^T per head, written f32 into the attn output region.
// grid (16,16,32): x = i-tile, y = j-tile, z = bh
// ---------------------------------------------------------------------------
__global__ __launch_bounds__(256) void k_scores(const short* __restrict__ Qb,
                                                const short* __restrict__ Kb,
                                                float* __restrict__ attn) {
  __shared__ __align__(16) short Qs[64][72];  // 72 = 64 + 8 pad (144B = 9*16B)
  __shared__ __align__(16) short Ks[64][72];
  const int tid = threadIdx.x;
  const int lane = tid & 63, wv = tid >> 6;
  const int i0 = blockIdx.x * 64, j0 = blockIdx.y * 64;
  const int bh = blockIdx.z;
  const long qbase = (long)((bh << 10) + i0) * DHD;
  const long kbase = (long)((bh << 10) + j0) * DHD;
#pragma unroll
  for (int t = 0; t < 2; ++t) {
    const int idx = tid + 256 * t;
    const int r = idx >> 3, c8 = (idx & 7) * 8;
    *reinterpret_cast<bf16x8*>(&Qs[r][c8]) =
        *reinterpret_cast<const bf16x8*>(&Qb[qbase + r * DHD + c8]);
    *reinterpret_cast<bf16x8*>(&Ks[r][c8]) =
        *reinterpret_cast<const bf16x8*>(&Kb[kbase + r * DHD + c8]);
  }
  __syncthreads();
  const f32x4 zero4 = {0.f, 0.f, 0.f, 0.f};
  f32x4 acc[4] = {zero4, zero4, zero4, zero4};
  const int rq = wv * 16 + (lane & 15);
#pragma unroll
  for (int ks = 0; ks < 2; ++ks) {
    const int kk = ks * 32 + (lane >> 4) * 8;
    const bf16x8 a = *reinterpret_cast<const bf16x8*>(&Qs[rq][kk]);
#pragma unroll
    for (int n = 0; n < 4; ++n) {
      const bf16x8 b = *reinterpret_cast<const bf16x8*>(&Ks[n * 16 + (lane & 15)][kk]);
      acc[n] = __builtin_amdgcn_mfma_f32_16x16x32_bf16(a, b, acc[n], 0, 0, 0);
    }
  }
  const long obase = ((long)bh << 20) +
                     ((long)(i0 + wv * 16 + ((lane >> 4) << 2)) << 10) + j0 + (lane & 15);
#pragma unroll
  for (int i = 0; i < 4; ++i) {
#pragma unroll
    for (int n = 0; n < 4; ++n) attn[obase + ((long)i << 10) + n * 16] = acc[n][i];
  }
}

// ---------------------------------------------------------------------------
// K3b: per-row: attn softmax (with LARGE_NEG masking) + dcl cos-softmax stats.
// Overwrites scores with final attn. grid (8, 1024, 4): x=h (fast, shares mask
// row in L2 across heads), y=i, z=b.
// ---------------------------------------------------------------------------
__global__ __launch_bounds__(256) void k_softmax(float* __restrict__ attn,
                                                 const float* __restrict__ mask,
                                                 const float* __restrict__ qn,
                                                 const float* __restrict__ kn,
                                                 float* __restrict__ accum) {
  const int h = blockIdx.x, i = blockIdx.y, b = blockIdx.z;
  const int bh = b * NH + h;
  float* row = attn + ((long)bh << 20) + ((long)i << 10);
  const float* mrow = mask + ((long)b << 20) + ((long)i << 10);
  const float* knr = kn + (bh << 10);
  const float inv_qt = 1.0f / (qn[(bh << 10) + i] * TEMPP);
  const int tid = threadIdx.x;
  const int wv = tid >> 6;

  float sv[4], mv[4], cv[4], lv[4];
  float ml = -3.4e38f, mc = -3.4e38f;
#pragma unroll
  for (int t = 0; t < 4; ++t) {
    const int j = tid + t * 256;
    sv[t] = row[j];
    mv[t] = mrow[j];
    lv[t] = (mv[t] == 0.0f) ? (LNEG * SCALE) : (sv[t] * SCALE);
    cv[t] = sv[t] * inv_qt / knr[j];
    ml = fmaxf(ml, lv[t]);
    mc = fmaxf(mc, cv[t]);
  }
  ml = wave_max(ml);
  mc = wave_max(mc);
  __shared__ float red[4][2];
  if ((tid & 63) == 0) { red[wv][0] = ml; red[wv][1] = mc; }
  __syncthreads();
  ml = fmaxf(fmaxf(red[0][0], red[1][0]), fmaxf(red[2][0], red[3][0]));
  mc = fmaxf(fmaxf(red[0][1], red[1][1]), fmaxf(red[2][1], red[3][1]));

  float Z = 0.f, alls = 0.f, pos = 0.f;
  float ev[4];
#pragma unroll
  for (int t = 0; t < 4; ++t) {
    ev[t] = __expf(lv[t] - ml);
    Z += ev[t];
    const float ec = __expf(cv[t] - mc);
    alls += ec;
    pos += ec * mv[t];
  }
  Z = wave_sum(Z);
  alls = wave_sum(alls);
  pos = wave_sum(pos);
  __shared__ float red2[4][3];
  if ((tid & 63) == 0) { red2[wv][0] = Z; red2[wv][1] = alls; red2[wv][2] = pos; }
  __syncthreads();
  Z = red2[0][0] + red2[1][0] + red2[2][0] + red2[3][0];
  alls = red2[0][1] + red2[1][1] + red2[2][1] + red2[3][1];
  pos = red2[0][2] + red2[1][2] + red2[2][2] + red2[3][2];

  const float rZ = 1.0f / Z;
#pragma unroll
  for (int t = 0; t < 4; ++t) row[tid + t * 256] = ev[t] * rZ;

  if (tid == 0) atomicAdd(accum, logf(alls) - logf(pos));
}

// ---------------------------------------------------------------------------
// K3c: out_av = attn @ v, written bf16 in (B, N, H*DH).
// grid (16, 32): x = i-tile, y = bh
// ---------------------------------------------------------------------------
__global__ __launch_bounds__(256) void k_pv(const float* __restrict__ attn,
                                            const short* __restrict__ VbT,
                                            short* __restrict__ AVb) {
  __shared__ __align__(16) short As[64][40];
  __shared__ __align__(16) short Bs[64][40];
  const int tid = threadIdx.x;
  const int lane = tid & 63, wv = tid >> 6;
  const int i0 = blockIdx.x * 64;
  const int bh = blockIdx.y;
  const float* arow = attn + ((long)bh << 20);
  const short* vt = VbT + ((long)bh << 16);
  const f32x4 zero4 = {0.f, 0.f, 0.f, 0.f};
  f32x4 acc[4] = {zero4, zero4, zero4, zero4};
  const int sr = tid >> 3, sc = (tid & 7) * 4;  // A staging (f32 src)
  const int br = tid >> 2, bc = (tid & 3) * 8;  // B staging (bf16 src)

  for (int ks = 0; ks < 32; ++ks) {
    const int jk = ks * 32;
    __syncthreads();
#pragma unroll
    for (int t = 0; t < 2; ++t) {
      const int r = sr + t * 32;
      const f32x4 va = *reinterpret_cast<const f32x4*>(&arow[((long)(i0 + r) << 10) + jk + sc]);
      bf16x4 pa;
#pragma unroll
      for (int i2 = 0; i2 < 4; ++i2) pa[i2] = f2bf(va[i2]);
      *reinterpret_cast<bf16x4*>(&As[r][sc]) = pa;
    }
    *reinterpret_cast<bf16x8*>(&Bs[br][bc]) =
        *reinterpret_cast<const bf16x8*>(&vt[((long)br << 10) + jk + bc]);
    __syncthreads();
    const int kk = (lane >> 4) * 8;
    const bf16x8 a = *reinterpret_cast<const bf16x8*>(&As[wv * 16 + (lane & 15)][kk]);
#pragma unroll
    for (int n = 0; n < 4; ++n) {
      const bf16x8 b = *reinterpret_cast<const bf16x8*>(&Bs[n * 16 + (lane & 15)][kk]);
      acc[n] = __builtin_amdgcn_mfma_f32_16x16x32_bf16(a, b, acc[n], 0, 0, 0);
    }
  }
  const int b = bh >> 3, h = bh & 7;
  const int rbase = i0 + wv * 16 + ((lane >> 4) << 2);
#pragma unroll
  for (int i = 0; i < 4; ++i) {
    const long orow = ((long)((b << 10) + rbase + i) << 9) + h * 64;
#pragma unroll
    for (int n = 0; n < 4; ++n) AVb[orow + n * 16 + (lane & 15)] = f2bf(acc[n][i]);
  }
}

// ---------------------------------------------------------------------------
// K4: out = av @ Wo.T + bo (f32 out). grid (64, 8).
// ---------------------------------------------------------------------------
__global__ __launch_bounds__(256) void k_outproj(const short* __restrict__ AVb,
                                                 const float* __restrict__ Wo,
                                                 const float* __restrict__ bo,
                                                 float* __restrict__ out) {
  __shared__ __align__(16) short As[64][40];
  __shared__ __align__(16) short Bs[64][40];
  const int tid = threadIdx.x;
  const int lane = tid & 63, wv = tid >> 6;
  const int m0 = blockIdx.x * 64, o0 = blockIdx.y * 64;
  const f32x4 zero4 = {0.f, 0.f, 0.f, 0.f};
  f32x4 acc[4] = {zero4, zero4, zero4, zero4};
  const int ar = tid >> 2, ac = (tid & 3) * 8;    // A staging (bf16 src)
  const int br2 = tid >> 3, bc4 = (tid & 7) * 4;  // B staging (f32 src)

  for (int ks = 0; ks < 16; ++ks) {
    const int k0 = ks * 32;
    __syncthreads();
    *reinterpret_cast<bf16x8*>(&As[ar][ac]) =
        *reinterpret_cast<const bf16x8*>(&AVb[((long)(m0 + ar) << 9) + k0 + ac]);
#pragma unroll
    for (int t = 0; t < 2; ++t) {
      const int r = br2 + t * 32;
      const f32x4 vb = *reinterpret_cast<const f32x4*>(&Wo[(o0 + r) * DIMD + k0 + bc4]);
      bf16x4 pb;
#pragma unroll
      for (int i2 = 0; i2 < 4; ++i2) pb[i2] = f2bf(vb[i2]);
      *reinterpret_cast<bf16x4*>(&Bs[r][bc4]) = pb;
    }
    __syncthreads();
    const int kk = (lane >> 4) * 8;
    const bf16x8 a = *reinterpret_cast<const bf16x8*>(&As[wv * 16 + (lane & 15)][kk]);
#pragma unroll
    for (int n = 0; n < 4; ++n) {
      const bf16x8 b = *reinterpret_cast<const bf16x8*>(&Bs[n * 16 + (lane & 15)][kk]);
      acc[n] = __builtin_amdgcn_mfma_f32_16x16x32_bf16(a, b, acc[n], 0, 0, 0);
    }
  }
  const int rbase = m0 + wv * 16 + ((lane >> 4) << 2);
#pragma unroll
  for (int i = 0; i < 4; ++i) {
#pragma unroll
    for (int n = 0; n < 4; ++n) {
      const int o = o0 + n * 16 + (lane & 15);
      out[((long)(rbase + i) << 9) + o] = acc[n][i] + bo[o];
    }
  }
}

// ---------------------------------------------------------------------------
// K5: finalize dcl scalar
// ---------------------------------------------------------------------------
__global__ void k_finalize(const float* __restrict__ accum, float* __restrict__ dcl) {
  if (threadIdx.x == 0) {
    const float cl = accum[0];
    const float rg = accum[1];
    *dcl = cl / (float)(NB * NH * NN) + KREG * rg / ((float)NN * (float)(NN - 1)) / (float)NB;
  }
}

extern "C" void kernel_launch(void* const* d_in, const int* in_sizes, int n_in,
                              void* d_out, int out_size, void* d_ws, size_t ws_size,
                              hipStream_t stream) {
  const float* x = (const float*)d_in[0];
  const float* mask = (const float*)d_in[1];
  const float* Wq = (const float*)d_in[2];
  const float* bq = (const float*)d_in[3];
  const float* Wk = (const float*)d_in[4];
  const float* bk = (const float*)d_in[5];
  const float* Wv = (const float*)d_in[6];
  const float* bv = (const float*)d_in[7];
  const float* Wo = (const float*)d_in[8];
  const float* bo = (const float*)d_in[9];

  float* out = (float*)d_out;                          // B*N*DIM      = 2,097,152
  float* attn = out + (size_t)NB * NN * DIMD;          // B*H*N*N      = 33,554,432
  float* dcl = attn + (size_t)NB * NH * NN * NN;       // 1

  char* ws = (char*)d_ws;
  short* Qb = (short*)(ws);                            // 4 MB bf16 (B,H,N,DH)
  short* Kb = (short*)(ws + ((size_t)4 << 20));
  short* Vb = (short*)(ws + ((size_t)8 << 20));
  short* VbT = (short*)(ws + ((size_t)12 << 20));      // (B,H,DH,N)
  short* AVb = (short*)(ws + ((size_t)16 << 20));      // (B,N,INNER)
  float* qn = (float*)(ws + ((size_t)20 << 20));       // 128 KB
  float* kn = (float*)(ws + ((size_t)20 << 20) + (1 << 18));
  float* accum = (float*)(ws + ((size_t)20 << 20) + (2 << 18));  // [cl, reg]

  hipMemsetAsync(accum, 0, 2 * sizeof(float), stream);

  k_qkv<<<dim3(64, 24), 256, 0, stream>>>(x, Wq, bq, Wk, bk, Wv, bv, Qb, Kb, Vb, qn, kn);
  k_vtrans<<<dim3(16, 32), 256, 0, stream>>>(Vb, VbT);
  k_regular<<<dim3(1024), 256, 0, stream>>>(mask, accum);
  k_scores<<<dim3(16, 16, 32), 256, 0, stream>>>(Qb, Kb, attn);
  k_softmax<<<dim3(8, 1024, 4), 256, 0, stream>>>(attn, mask, qn, kn, accum);
  k_pv<<<dim3(16, 32), 256, 0, stream>>>(attn, VbT, AVb);
  k_outproj<<<dim3(64, 8), 256, 0, stream>>>(AVb, Wo, bo, out);
  k_finalize<<<1, 64, 0, stream>>>(accum, dcl);
}

// Round 3
// 324.931 us; speedup vs baseline: 2.2020x; 2.2020x over previous
//
#include <hip/hip_runtime.h>
#include <hip/hip_bf16.h>
#include <math.h>

#define NB 4
#define NN 1024
#define DIMD 512
#define NH 8
#define DHD 64
#define INNERD 512
#define SCALE 0.125f
#define TEMPP 0.1f
#define KREG 0.3f
#define LNEG -23.025850929940457f

typedef __attribute__((ext_vector_type(8))) short bf16x8;
typedef __attribute__((ext_vector_type(4))) short bf16x4;
typedef __attribute__((ext_vector_type(4))) float f32x4;

static __device__ __forceinline__ short f2bf(float f) {
  unsigned u = __float_as_uint(f);
  u += 0x7fffu + ((u >> 16) & 1u);
  return (short)(u >> 16);
}
static __device__ __forceinline__ float bf2f(short s) {
  unsigned u = ((unsigned)(unsigned short)s) << 16;
  return __uint_as_float(u);
}

static __device__ __forceinline__ float wave_sum(float v) {
#pragma unroll
  for (int o = 1; o < 64; o <<= 1) v += __shfl_xor(v, o, 64);
  return v;
}
// reductions over 16-lane groups (stay within wave)
static __device__ __forceinline__ float g16_max(float v) {
#pragma unroll
  for (int o = 1; o < 16; o <<= 1) v = fmaxf(v, __shfl_xor(v, o, 64));
  return v;
}
static __device__ __forceinline__ float g16_sum(float v) {
#pragma unroll
  for (int o = 1; o < 16; o <<= 1) v += __shfl_xor(v, o, 64);
  return v;
}

// ---------------------------------------------------------------------------
// K1: fused QKV projection. out = x @ W.T + b, written bf16 in (B,H,N,DH).
// qn stores 1/(||q||*TEMP), kn stores 1/||k|| (pre-reciprocated for k_attn).
// grid (64, 24)
// ---------------------------------------------------------------------------
__global__ __launch_bounds__(256) void k_qkv(
    const float* __restrict__ x,
    const float* __restrict__ Wq, const float* __restrict__ bq,
    const float* __restrict__ Wk, const float* __restrict__ bk,
    const float* __restrict__ Wv, const float* __restrict__ bv,
    short* __restrict__ Qb, short* __restrict__ Kb, short* __restrict__ Vb,
    float* __restrict__ qn, float* __restrict__ kn) {
  __shared__ __align__(16) short As[64][40];
  __shared__ __align__(16) short Bs[64][40];
  const int tid = threadIdx.x;
  const int lane = tid & 63;
  const int wv = tid >> 6;
  const int m0 = blockIdx.x * 64;
  const int oc = blockIdx.y;
  const int which = oc >> 3;  // 0=q 1=k 2=v
  const int h = oc & 7;
  const float* W = (which == 0) ? Wq : (which == 1) ? Wk : Wv;
  const float* bias = (which == 0) ? bq : (which == 1) ? bk : bv;
  short* Out = (which == 0) ? Qb : (which == 1) ? Kb : Vb;
  const int o0 = h * 64;

  const f32x4 zero4 = {0.f, 0.f, 0.f, 0.f};
  f32x4 acc[4] = {zero4, zero4, zero4, zero4};

  const int sr = tid >> 3;
  const int sc = (tid & 7) * 4;

  for (int ks = 0; ks < 16; ++ks) {
    const int k0 = ks * 32;
    __syncthreads();
#pragma unroll
    for (int t = 0; t < 2; ++t) {
      const int r = sr + t * 32;
      const f32x4 va = *reinterpret_cast<const f32x4*>(&x[(m0 + r) * DIMD + k0 + sc]);
      const f32x4 vb = *reinterpret_cast<const f32x4*>(&W[(o0 + r) * DIMD + k0 + sc]);
      bf16x4 pa, pb;
#pragma unroll
      for (int i2 = 0; i2 < 4; ++i2) { pa[i2] = f2bf(va[i2]); pb[i2] = f2bf(vb[i2]); }
      *reinterpret_cast<bf16x4*>(&As[r][sc]) = pa;
      *reinterpret_cast<bf16x4*>(&Bs[r][sc]) = pb;
    }
    __syncthreads();
    const int kk = (lane >> 4) * 8;
    const bf16x8 a = *reinterpret_cast<const bf16x8*>(&As[wv * 16 + (lane & 15)][kk]);
#pragma unroll
    for (int n = 0; n < 4; ++n) {
      const bf16x8 b = *reinterpret_cast<const bf16x8*>(&Bs[n * 16 + (lane & 15)][kk]);
      acc[n] = __builtin_amdgcn_mfma_f32_16x16x32_bf16(a, b, acc[n], 0, 0, 0);
    }
  }

  const int colb = lane & 15;
  const int rbase = m0 + wv * 16 + ((lane >> 4) << 2);
  const int bidx = m0 >> 10;
  const int hb = (bidx * NH + h) << 10;
  float p2[4] = {0.f, 0.f, 0.f, 0.f};
#pragma unroll
  for (int n = 0; n < 4; ++n) {
    const float bval = bias[o0 + n * 16 + colb];
#pragma unroll
    for (int i = 0; i < 4; ++i) {
      const float val = acc[n][i] + bval;
      p2[i] += val * val;
      const int m = rbase + i;
      Out[(long)(hb + (m & (NN - 1))) * DHD + n * 16 + colb] = f2bf(val);
    }
  }
  if (which < 2) {
    float* norm = (which == 0) ? qn : kn;
#pragma unroll
    for (int off = 1; off < 16; off <<= 1) {
#pragma unroll
      for (int i = 0; i < 4; ++i) p2[i] += __shfl_xor(p2[i], off, 64);
    }
    if (colb == 0) {
#pragma unroll
      for (int i = 0; i < 4; ++i) {
        const int m = rbase + i;
        const float nv = sqrtf(p2[i]);
        norm[hb + (m & (NN - 1))] = (which == 0) ? (1.0f / (nv * TEMPP)) : (1.0f / nv);
      }
    }
  }
}

// ---------------------------------------------------------------------------
// K1.5: transpose V: (bh, j, d) -> (bh, d, j). grid (16, 32)
// ---------------------------------------------------------------------------
__global__ __launch_bounds__(256) void k_vtrans(const short* __restrict__ Vb,
                                                short* __restrict__ VbT) {
  __shared__ __align__(16) short T[64][72];
  const int tid = threadIdx.x;
  const int bh = blockIdx.y;
  const int j0 = blockIdx.x * 64;
#pragma unroll
  for (int t = 0; t < 2; ++t) {
    const int idx = tid + 256 * t;
    const int r = idx >> 3, c8 = (idx & 7) * 8;
    *reinterpret_cast<bf16x8*>(&T[r][c8]) =
        *reinterpret_cast<const bf16x8*>(&Vb[(long)((bh << 10) + j0 + r) * DHD + c8]);
  }
  __syncthreads();
  const int d = tid & 63;
  const int cg = tid >> 6;
#pragma unroll
  for (int t = 0; t < 2; ++t) {
    const int ch = cg * 2 + t;
    bf16x8 v;
#pragma unroll
    for (int jj = 0; jj < 8; ++jj) v[jj] = T[ch * 8 + jj][d];
    *reinterpret_cast<bf16x8*>(&VbT[((long)(bh * DHD + d) << 10) + j0 + ch * 8]) = v;
  }
}

// ---------------------------------------------------------------------------
// K2: regular sum: sum |eye - mask| -> accum[1]. grid (1024)
// ---------------------------------------------------------------------------
__global__ __launch_bounds__(256) void k_regular(const float* __restrict__ mask,
                                                 float* __restrict__ accum) {
  const int tid = threadIdx.x;
  float s = 0.f;
  const int total4 = (NB * NN * NN) / 4;
  for (int idx = blockIdx.x * 256 + tid; idx < total4; idx += gridDim.x * 256) {
    const f32x4 mv = *reinterpret_cast<const f32x4*>(&mask[(long)idx * 4]);
    const int flat = idx * 4;
    const int i = (flat >> 10) & (NN - 1);
    const int j = flat & (NN - 1);
#pragma unroll
    for (int c = 0; c < 4; ++c) {
      const float e = (j + c == i) ? 1.0f : 0.0f;
      s += fabsf(e - mv[c]);
    }
  }
  s = wave_sum(s);
  __shared__ float red[4];
  if ((tid & 63) == 0) red[tid >> 6] = s;
  __syncthreads();
  if (tid == 0) atomicAdd(accum + 1, red[0] + red[1] + red[2] + red[3]);
}

// ---------------------------------------------------------------------------
// K3: FUSED scores + dual softmax + dcl stats + PV.
// Block = 16 query rows of one (b,h). grid (64, 32), 256 threads.
// LDS: S[16][1032] bf16 (scores, later P). No atomics: per-block partial.
// ---------------------------------------------------------------------------
__global__ __launch_bounds__(256) void k_attn(
    const short* __restrict__ Qb, const short* __restrict__ Kb,
    const short* __restrict__ VbT,
    const float* __restrict__ mask,
    const float* __restrict__ qn, const float* __restrict__ kn,
    float* __restrict__ attn, short* __restrict__ AVb,
    float* __restrict__ partial) {
  __shared__ __align__(16) short S[16][1032];  // stride 2064B -> 4-bank row skew
  __shared__ float rowv[16];
  const int tid = threadIdx.x;
  const int lane = tid & 63;
  const int wv = tid >> 6;
  const int i0 = blockIdx.x * 16;
  const int bh = blockIdx.y;
  const int b = bh >> 3, h = bh & 7;

  // ---- phase 1: scores = Q K^T (each wave owns 256 j-columns) ----
  const int lr = lane & 15;   // fragment row/col
  const int lk = lane >> 4;   // k-slot
  const long qoff = (long)((bh << 10) + i0 + lr) * DHD + lk * 8;
  const bf16x8 a0 = *reinterpret_cast<const bf16x8*>(&Qb[qoff]);
  const bf16x8 a1 = *reinterpret_cast<const bf16x8*>(&Qb[qoff + 32]);
  const short* Kbase = &Kb[(long)(bh << 10) * DHD];
#pragma unroll
  for (int jt = 0; jt < 16; ++jt) {
    const int j0 = wv * 256 + jt * 16;
    const long koff = (long)(j0 + lr) * DHD + lk * 8;
    const bf16x8 b0 = *reinterpret_cast<const bf16x8*>(&Kbase[koff]);
    const bf16x8 b1 = *reinterpret_cast<const bf16x8*>(&Kbase[koff + 32]);
    f32x4 acc = {0.f, 0.f, 0.f, 0.f};
    acc = __builtin_amdgcn_mfma_f32_16x16x32_bf16(a0, b0, acc, 0, 0, 0);
    acc = __builtin_amdgcn_mfma_f32_16x16x32_bf16(a1, b1, acc, 0, 0, 0);
#pragma unroll
    for (int i = 0; i < 4; ++i) S[lk * 4 + i][j0 + lr] = f2bf(acc[i]);
  }
  __syncthreads();

  // ---- phase 2: dual softmax. row r handled by 16 threads (sub) ----
  const int r = tid >> 4, sub = tid & 15;
  const int gi = i0 + r;
  const float* mrow = mask + ((long)b << 20) + ((long)gi << 10);
  const float* knr = kn + (bh << 10);  // holds 1/||k||
  const float inv_qt = qn[(bh << 10) + gi];  // holds 1/(||q||*TEMP)

  float ml = -3.4e38f, mc = -3.4e38f;
  unsigned long long mb = 0ull;
#pragma unroll
  for (int k = 0; k < 8; ++k) {
    const int c0 = sub * 8 + k * 128;
    const bf16x8 sv = *reinterpret_cast<const bf16x8*>(&S[r][c0]);
    const f32x4 mv0 = *reinterpret_cast<const f32x4*>(&mrow[c0]);
    const f32x4 mv1 = *reinterpret_cast<const f32x4*>(&mrow[c0 + 4]);
    const f32x4 kn0 = *reinterpret_cast<const f32x4*>(&knr[c0]);
    const f32x4 kn1 = *reinterpret_cast<const f32x4*>(&knr[c0 + 4]);
#pragma unroll
    for (int e = 0; e < 8; ++e) {
      const float s = bf2f(sv[e]);
      const float mval = (e < 4) ? mv0[e] : mv1[e - 4];
      const float rk = (e < 4) ? kn0[e] : kn1[e - 4];
      const float lv = (mval == 0.0f) ? (LNEG * SCALE) : (s * SCALE);
      const float cv = s * inv_qt * rk;
      if (mval != 0.0f) mb |= (1ull << (k * 8 + e));
      ml = fmaxf(ml, lv);
      mc = fmaxf(mc, cv);
    }
  }
  ml = g16_max(ml);
  mc = g16_max(mc);

  float Z = 0.f, alls = 0.f, pos = 0.f;
  float ev[64];
#pragma unroll
  for (int k = 0; k < 8; ++k) {
    const int c0 = sub * 8 + k * 128;
    const bf16x8 sv = *reinterpret_cast<const bf16x8*>(&S[r][c0]);
    const f32x4 kn0 = *reinterpret_cast<const f32x4*>(&knr[c0]);
    const f32x4 kn1 = *reinterpret_cast<const f32x4*>(&knr[c0 + 4]);
#pragma unroll
    for (int e = 0; e < 8; ++e) {
      const float s = bf2f(sv[e]);
      const float rk = (e < 4) ? kn0[e] : kn1[e - 4];
      const bool mset = (mb >> (k * 8 + e)) & 1ull;
      const float lv = mset ? (s * SCALE) : (LNEG * SCALE);
      const float cv = s * inv_qt * rk;
      const float e1 = __expf(lv - ml);
      const float ec = __expf(cv - mc);
      ev[k * 8 + e] = e1;
      Z += e1;
      alls += ec;
      pos += mset ? ec : 0.0f;
    }
  }
  Z = g16_sum(Z);
  alls = g16_sum(alls);
  pos = g16_sum(pos);

  // write final attn (f32, global) and P (bf16, back into S)
  float* arow = attn + ((long)bh << 20) + ((long)gi << 10);
  const float rZ = 1.0f / Z;
#pragma unroll
  for (int k = 0; k < 8; ++k) {
    const int c0 = sub * 8 + k * 128;
    f32x4 o0, o1;
    bf16x8 pb;
#pragma unroll
    for (int e = 0; e < 4; ++e) {
      o0[e] = ev[k * 8 + e] * rZ;
      o1[e] = ev[k * 8 + 4 + e] * rZ;
      pb[e] = f2bf(o0[e]);
      pb[4 + e] = f2bf(o1[e]);
    }
    *reinterpret_cast<f32x4*>(&arow[c0]) = o0;
    *reinterpret_cast<f32x4*>(&arow[c0 + 4]) = o1;
    *reinterpret_cast<bf16x8*>(&S[r][c0]) = pb;
  }
  if (sub == 0) rowv[r] = __logf(alls) - __logf(pos);
  __syncthreads();

  if (tid == 0) {
    float s = 0.f;
#pragma unroll
    for (int i = 0; i < 16; ++i) s += rowv[i];
    partial[bh * 64 + blockIdx.x] = s;
  }

  // ---- phase 3: PV. wave w owns d-tile w (16 cols). ----
  f32x4 acc = {0.f, 0.f, 0.f, 0.f};
  const short* vrow = &VbT[(long)(bh * DHD + wv * 16 + lr) << 10];
#pragma unroll 8
  for (int k0 = 0; k0 < 32; ++k0) {
    const bf16x8 a = *reinterpret_cast<const bf16x8*>(&S[lr][k0 * 32 + lk * 8]);
    const bf16x8 bb = *reinterpret_cast<const bf16x8*>(&vrow[k0 * 32 + lk * 8]);
    acc = __builtin_amdgcn_mfma_f32_16x16x32_bf16(a, bb, acc, 0, 0, 0);
  }
#pragma unroll
  for (int i = 0; i < 4; ++i) {
    const int row = i0 + lk * 4 + i;
    AVb[((long)((b << 10) + row) << 9) + h * DHD + wv * 16 + lr] = f2bf(acc[i]);
  }
}

// ---------------------------------------------------------------------------
// K4: out = av @ Wo.T + bo (f32 out). grid (64, 8).
// ---------------------------------------------------------------------------
__global__ __launch_bounds__(256) void k_outproj(const short* __restrict__ AVb,
                                                 const float* __restrict__ Wo,
                                                 const float* __restrict__ bo,
                                                 float* __restrict__ out) {
  __shared__ __align__(16) short As[64][40];
  __shared__ __align__(16) short Bs[64][40];
  const int tid = threadIdx.x;
  const int lane = tid & 63, wv = tid >> 6;
  const int m0 = blockIdx.x * 64, o0 = blockIdx.y * 64;
  const f32x4 zero4 = {0.f, 0.f, 0.f, 0.f};
  f32x4 acc[4] = {zero4, zero4, zero4, zero4};
  const int ar = tid >> 2, ac = (tid & 3) * 8;
  const int br2 = tid >> 3, bc4 = (tid & 7) * 4;

  for (int ks = 0; ks < 16; ++ks) {
    const int k0 = ks * 32;
    __syncthreads();
    *reinterpret_cast<bf16x8*>(&As[ar][ac]) =
        *reinterpret_cast<const bf16x8*>(&AVb[((long)(m0 + ar) << 9) + k0 + ac]);
#pragma unroll
    for (int t = 0; t < 2; ++t) {
      const int rr = br2 + t * 32;
      const f32x4 vb = *reinterpret_cast<const f32x4*>(&Wo[(o0 + rr) * DIMD + k0 + bc4]);
      bf16x4 pb;
#pragma unroll
      for (int i2 = 0; i2 < 4; ++i2) pb[i2] = f2bf(vb[i2]);
      *reinterpret_cast<bf16x4*>(&Bs[rr][bc4]) = pb;
    }
    __syncthreads();
    const int kk = (lane >> 4) * 8;
    const bf16x8 a = *reinterpret_cast<const bf16x8*>(&As[wv * 16 + (lane & 15)][kk]);
#pragma unroll
    for (int n = 0; n < 4; ++n) {
      const bf16x8 b = *reinterpret_cast<const bf16x8*>(&Bs[n * 16 + (lane & 15)][kk]);
      acc[n] = __builtin_amdgcn_mfma_f32_16x16x32_bf16(a, b, acc[n], 0, 0, 0);
    }
  }
  const int rbase = m0 + wv * 16 + ((lane >> 4) << 2);
#pragma unroll
  for (int i = 0; i < 4; ++i) {
#pragma unroll
    for (int n = 0; n < 4; ++n) {
      const int o = o0 + n * 16 + (lane & 15);
      out[((long)(rbase + i) << 9) + o] = acc[n][i] + bo[o];
    }
  }
}

// ---------------------------------------------------------------------------
// K5: finalize dcl: reduce 2048 per-block partials + regular term
// ---------------------------------------------------------------------------
__global__ __launch_bounds__(256) void k_finalize(const float* __restrict__ partial,
                                                  const float* __restrict__ accum,
                                                  float* __restrict__ dcl) {
  const int tid = threadIdx.x;
  float s = 0.f;
#pragma unroll
  for (int t = 0; t < 8; ++t) s += partial[tid + t * 256];
  s = wave_sum(s);
  __shared__ float red[4];
  if ((tid & 63) == 0) red[tid >> 6] = s;
  __syncthreads();
  if (tid == 0) {
    const float cl = red[0] + red[1] + red[2] + red[3];
    const float rg = accum[1];
    *dcl = cl / (float)(NB * NH * NN) + KREG * rg / ((float)NN * (float)(NN - 1)) / (float)NB;
  }
}

extern "C" void kernel_launch(void* const* d_in, const int* in_sizes, int n_in,
                              void* d_out, int out_size, void* d_ws, size_t ws_size,
                              hipStream_t stream) {
  const float* x = (const float*)d_in[0];
  const float* mask = (const float*)d_in[1];
  const float* Wq = (const float*)d_in[2];
  const float* bq = (const float*)d_in[3];
  const float* Wk = (const float*)d_in[4];
  const float* bk = (const float*)d_in[5];
  const float* Wv = (const float*)d_in[6];
  const float* bv = (const float*)d_in[7];
  const float* Wo = (const float*)d_in[8];
  const float* bo = (const float*)d_in[9];

  float* out = (float*)d_out;
  float* attn = out + (size_t)NB * NN * DIMD;
  float* dcl = attn + (size_t)NB * NH * NN * NN;

  char* ws = (char*)d_ws;
  short* Qb = (short*)(ws);
  short* Kb = (short*)(ws + ((size_t)4 << 20));
  short* Vb = (short*)(ws + ((size_t)8 << 20));
  short* VbT = (short*)(ws + ((size_t)12 << 20));
  short* AVb = (short*)(ws + ((size_t)16 << 20));
  float* qn = (float*)(ws + ((size_t)20 << 20));
  float* kn = (float*)(ws + ((size_t)20 << 20) + (1 << 18));
  float* accum = (float*)(ws + ((size_t)20 << 20) + (2 << 18));
  float* partial = (float*)(ws + ((size_t)20 << 20) + (3 << 18));  // 2048 f32

  hipMemsetAsync(accum, 0, 2 * sizeof(float), stream);

  k_qkv<<<dim3(64, 24), 256, 0, stream>>>(x, Wq, bq, Wk, bk, Wv, bv, Qb, Kb, Vb, qn, kn);
  k_vtrans<<<dim3(16, 32), 256, 0, stream>>>(Vb, VbT);
  k_regular<<<dim3(1024), 256, 0, stream>>>(mask, accum);
  k_attn<<<dim3(64, 32), 256, 0, stream>>>(Qb, Kb, VbT, mask, qn, kn, attn, AVb, partial);
  k_outproj<<<dim3(64, 8), 256, 0, stream>>>(AVb, Wo, bo, out);
  k_finalize<<<1, 256, 0, stream>>>(partial, accum, dcl);
}

// Round 6
// 302.430 us; speedup vs baseline: 2.3658x; 1.0744x over previous
//
#include <hip/hip_runtime.h>
#include <hip/hip_bf16.h>
#include <math.h>

#define NB 4
#define NN 1024
#define DIMD 512
#define NH 8
#define DHD 64
#define INNERD 512
#define SCALE 0.125f
#define TEMPP 0.1f
#define KREG 0.3f
#define LNEG -23.025850929940457f

typedef __attribute__((ext_vector_type(8))) short bf16x8;
typedef __attribute__((ext_vector_type(4))) short bf16x4;
typedef __attribute__((ext_vector_type(4))) float f32x4;

static __device__ __forceinline__ short f2bf(float f) {
  unsigned u = __float_as_uint(f);
  u += 0x7fffu + ((u >> 16) & 1u);
  return (short)(u >> 16);
}
static __device__ __forceinline__ float bf2f(short s) {
  unsigned u = ((unsigned)(unsigned short)s) << 16;
  return __uint_as_float(u);
}

static __device__ __forceinline__ float wave_sum(float v) {
#pragma unroll
  for (int o = 1; o < 64; o <<= 1) v += __shfl_xor(v, o, 64);
  return v;
}
static __device__ __forceinline__ float wave_min(float v) {
#pragma unroll
  for (int o = 1; o < 64; o <<= 1) v = fminf(v, __shfl_xor(v, o, 64));
  return v;
}
static __device__ __forceinline__ float g16_sum(float v) {
#pragma unroll
  for (int o = 1; o < 16; o <<= 1) v += __shfl_xor(v, o, 64);
  return v;
}

// ---------------------------------------------------------------------------
// K1: fused QKV projection. out = x @ W.T + b, written bf16 in (B,H,N,DH).
// qn stores 1/(||q||*TEMP), kn stores 1/||k||. grid (64, 24)
// ---------------------------------------------------------------------------
__global__ __launch_bounds__(256) void k_qkv(
    const float* __restrict__ x,
    const float* __restrict__ Wq, const float* __restrict__ bq,
    const float* __restrict__ Wk, const float* __restrict__ bk,
    const float* __restrict__ Wv, const float* __restrict__ bv,
    short* __restrict__ Qb, short* __restrict__ Kb, short* __restrict__ Vb,
    float* __restrict__ qn, float* __restrict__ kn) {
  __shared__ __align__(16) short As[64][40];
  __shared__ __align__(16) short Bs[64][40];
  const int tid = threadIdx.x;
  const int lane = tid & 63;
  const int wv = tid >> 6;
  const int m0 = blockIdx.x * 64;
  const int oc = blockIdx.y;
  const int which = oc >> 3;  // 0=q 1=k 2=v
  const int h = oc & 7;
  const float* W = (which == 0) ? Wq : (which == 1) ? Wk : Wv;
  const float* bias = (which == 0) ? bq : (which == 1) ? bk : bv;
  short* Out = (which == 0) ? Qb : (which == 1) ? Kb : Vb;
  const int o0 = h * 64;

  const f32x4 zero4 = {0.f, 0.f, 0.f, 0.f};
  f32x4 acc[4] = {zero4, zero4, zero4, zero4};

  const int sr = tid >> 3;
  const int sc = (tid & 7) * 4;

  for (int ks = 0; ks < 16; ++ks) {
    const int k0 = ks * 32;
    __syncthreads();
#pragma unroll
    for (int t = 0; t < 2; ++t) {
      const int r = sr + t * 32;
      const f32x4 va = *reinterpret_cast<const f32x4*>(&x[(m0 + r) * DIMD + k0 + sc]);
      const f32x4 vb = *reinterpret_cast<const f32x4*>(&W[(o0 + r) * DIMD + k0 + sc]);
      bf16x4 pa, pb;
#pragma unroll
      for (int i2 = 0; i2 < 4; ++i2) { pa[i2] = f2bf(va[i2]); pb[i2] = f2bf(vb[i2]); }
      *reinterpret_cast<bf16x4*>(&As[r][sc]) = pa;
      *reinterpret_cast<bf16x4*>(&Bs[r][sc]) = pb;
    }
    __syncthreads();
    const int kk = (lane >> 4) * 8;
    const bf16x8 a = *reinterpret_cast<const bf16x8*>(&As[wv * 16 + (lane & 15)][kk]);
#pragma unroll
    for (int n = 0; n < 4; ++n) {
      const bf16x8 b = *reinterpret_cast<const bf16x8*>(&Bs[n * 16 + (lane & 15)][kk]);
      acc[n] = __builtin_amdgcn_mfma_f32_16x16x32_bf16(a, b, acc[n], 0, 0, 0);
    }
  }

  const int colb = lane & 15;
  const int rbase = m0 + wv * 16 + ((lane >> 4) << 2);
  const int bidx = m0 >> 10;
  const int hb = (bidx * NH + h) << 10;
  float p2[4] = {0.f, 0.f, 0.f, 0.f};
#pragma unroll
  for (int n = 0; n < 4; ++n) {
    const float bval = bias[o0 + n * 16 + colb];
#pragma unroll
    for (int i = 0; i < 4; ++i) {
      const float val = acc[n][i] + bval;
      p2[i] += val * val;
      const int m = rbase + i;
      Out[(long)(hb + (m & (NN - 1))) * DHD + n * 16 + colb] = f2bf(val);
    }
  }
  if (which < 2) {
    float* norm = (which == 0) ? qn : kn;
#pragma unroll
    for (int off = 1; off < 16; off <<= 1) {
#pragma unroll
      for (int i = 0; i < 4; ++i) p2[i] += __shfl_xor(p2[i], off, 64);
    }
    if (colb == 0) {
#pragma unroll
      for (int i = 0; i < 4; ++i) {
        const int m = rbase + i;
        const float nv = sqrtf(p2[i]);
        norm[hb + (m & (NN - 1))] = (which == 0) ? (1.0f / (nv * TEMPP)) : (1.0f / nv);
      }
    }
  }
}

// ---------------------------------------------------------------------------
// K1.5: transpose V: (bh, j, d) -> (bh, d, j). grid (16, 32)
// ---------------------------------------------------------------------------
__global__ __launch_bounds__(256) void k_vtrans(const short* __restrict__ Vb,
                                                short* __restrict__ VbT) {
  __shared__ __align__(16) short T[64][72];
  const int tid = threadIdx.x;
  const int bh = blockIdx.y;
  const int j0 = blockIdx.x * 64;
#pragma unroll
  for (int t = 0; t < 2; ++t) {
    const int idx = tid + 256 * t;
    const int r = idx >> 3, c8 = (idx & 7) * 8;
    *reinterpret_cast<bf16x8*>(&T[r][c8]) =
        *reinterpret_cast<const bf16x8*>(&Vb[(long)((bh << 10) + j0 + r) * DHD + c8]);
  }
  __syncthreads();
  const int d = tid & 63;
  const int cg = tid >> 6;
#pragma unroll
  for (int t = 0; t < 2; ++t) {
    const int ch = cg * 2 + t;
    bf16x8 v;
#pragma unroll
    for (int jj = 0; jj < 8; ++jj) v[jj] = T[ch * 8 + jj][d];
    *reinterpret_cast<bf16x8*>(&VbT[((long)(bh * DHD + d) << 10) + j0 + ch * 8]) = v;
  }
}

// ---------------------------------------------------------------------------
// K2: per-(b,h) softmax bound: kms[bh] = max_j ||k_j|| * SCALE / TEMP.
// kn holds 1/||k|| -> max||k|| = 1/min(kn). grid (32), 256 threads.
// ---------------------------------------------------------------------------
__global__ __launch_bounds__(256) void k_kmax(const float* __restrict__ kn,
                                              float* __restrict__ kms) {
  const int tid = threadIdx.x;
  const int bh = blockIdx.x;
  const f32x4 v = *reinterpret_cast<const f32x4*>(&kn[(bh << 10) + tid * 4]);
  float m = fminf(fminf(v[0], v[1]), fminf(v[2], v[3]));
  m = wave_min(m);
  __shared__ float red[4];
  if ((tid & 63) == 0) red[tid >> 6] = m;
  __syncthreads();
  if (tid == 0) {
    const float mn = fminf(fminf(red[0], red[1]), fminf(red[2], red[3]));
    kms[bh] = (1.0f / mn) * SCALE / TEMPP;
  }
}

// swizzled LDS accessor: row stride 2048 B, XOR bits 4..6 with (r&7)
static __device__ __forceinline__ short* sp(short* S, int r, int c) {
  return (short*)((char*)S + (((r << 11) + (c << 1)) ^ ((r & 7) << 4)));
}

// ---------------------------------------------------------------------------
// K3: FUSED scores + single-pass dual softmax (bound-based, no max pass)
//     + dcl stats + mask-regular popcount + PV.
// Block = 16 query rows of one (b,h). grid (64, 32), 256 threads.
// ---------------------------------------------------------------------------
__global__ __launch_bounds__(256) void k_attn(
    const short* __restrict__ Qb, const short* __restrict__ Kb,
    const short* __restrict__ VbT,
    const float* __restrict__ mask,
    const float* __restrict__ qn, const float* __restrict__ kn,
    const float* __restrict__ kms,
    float* __restrict__ attn, short* __restrict__ AVb,
    float* __restrict__ partial, float* __restrict__ partial2) {
  __shared__ short S[16 * 1024];  // bf16 scores, then bf16 ev (unnormalized P)
  __shared__ float rowv[16];      // per-row log(alls)-log(pos)
  __shared__ float rowscale[16];  // per-row 1/Z
  __shared__ float rowc[16];      // per-row mask popcount (h==0 only)
  const int tid = threadIdx.x;
  const int lane = tid & 63;
  const int wv = tid >> 6;
  const int i0 = blockIdx.x * 16;
  const int bh = blockIdx.y;
  const int b = bh >> 3, h = bh & 7;

  // ---- phase 1: scores = Q K^T (each wave owns 256 j-columns) ----
  const int lr = lane & 15;
  const int lk = lane >> 4;
  const long qoff = (long)((bh << 10) + i0 + lr) * DHD + lk * 8;
  const bf16x8 a0 = *reinterpret_cast<const bf16x8*>(&Qb[qoff]);
  const bf16x8 a1 = *reinterpret_cast<const bf16x8*>(&Qb[qoff + 32]);
  const short* Kbase = &Kb[(long)(bh << 10) * DHD];
#pragma unroll
  for (int jt = 0; jt < 16; ++jt) {
    const int j0 = wv * 256 + jt * 16;
    const long koff = (long)(j0 + lr) * DHD + lk * 8;
    const bf16x8 b0 = *reinterpret_cast<const bf16x8*>(&Kbase[koff]);
    const bf16x8 b1 = *reinterpret_cast<const bf16x8*>(&Kbase[koff + 32]);
    f32x4 acc = {0.f, 0.f, 0.f, 0.f};
    acc = __builtin_amdgcn_mfma_f32_16x16x32_bf16(a0, b0, acc, 0, 0, 0);
    acc = __builtin_amdgcn_mfma_f32_16x16x32_bf16(a1, b1, acc, 0, 0, 0);
#pragma unroll
    for (int i = 0; i < 4; ++i) *sp(S, lk * 4 + i, j0 + lr) = f2bf(acc[i]);
  }
  __syncthreads();

  // ---- phase 2: single-pass dual softmax. row r by 16 threads (sub) ----
  const int r = tid >> 4, sub = tid & 15;
  const int gi = i0 + r;
  const float* mrow = mask + ((long)b << 20) + ((long)gi << 10);
  const float* knr = kn + (bh << 10);
  const float inv_qt = qn[(bh << 10) + gi];      // = 1/(||q||*TEMP)
  const float mlb = kms[bh] / inv_qt;            // = ||q||*kmax*SCALE >= max logit
  const float argM = LNEG * SCALE - mlb;         // masked-out logit arg

  float Z = 0.f, alls = 0.f, pos = 0.f, cntf = 0.f;
  bf16x8 pb[8];
#pragma unroll
  for (int k = 0; k < 8; ++k) {
    const int c0 = sub * 8 + k * 128;
    const bf16x8 sv = *reinterpret_cast<const bf16x8*>(sp(S, r, c0));
    const f32x4 mv0 = *reinterpret_cast<const f32x4*>(&mrow[c0]);
    const f32x4 mv1 = *reinterpret_cast<const f32x4*>(&mrow[c0 + 4]);
    const f32x4 kn0 = *reinterpret_cast<const f32x4*>(&knr[c0]);
    const f32x4 kn1 = *reinterpret_cast<const f32x4*>(&knr[c0 + 4]);
    bf16x8 p;
#pragma unroll
    for (int e = 0; e < 8; ++e) {
      const float s = bf2f(sv[e]);
      const float mval = (e < 4) ? mv0[e] : mv1[e - 4];
      const float rk = (e < 4) ? kn0[e] : kn1[e - 4];
      const bool mset = (mval != 0.0f);
      const float a1v = mset ? (s * SCALE - mlb) : argM;
      const float ev = __expf(a1v);                              // <= 1
      const float ec = __expf(s * inv_qt * rk - 1.0f / TEMPP);   // cos bound = 1/TEMP
      Z += ev;
      alls += ec;
      pos += mset ? ec : 0.0f;
      cntf += mset ? 1.0f : 0.0f;
      p[e] = f2bf(ev);
    }
    pb[k] = p;
    *reinterpret_cast<bf16x8*>(sp(S, r, c0)) = p;  // overwrite scores with ev
  }
  Z = g16_sum(Z);
  alls = g16_sum(alls);
  pos = g16_sum(pos);
  const float rZ = 1.0f / Z;
  if (sub == 0) { rowv[r] = __logf(alls) - __logf(pos); rowscale[r] = rZ; }
  if (h == 0) {
    cntf = g16_sum(cntf);
    if (sub == 0) rowc[r] = cntf;
  }
  __syncthreads();

  // attn write (own rows; ev kept in regs)
  float* arow = attn + ((long)bh << 20) + ((long)gi << 10);
#pragma unroll
  for (int k = 0; k < 8; ++k) {
    const int c0 = sub * 8 + k * 128;
    f32x4 o0, o1;
#pragma unroll
    for (int e = 0; e < 4; ++e) {
      o0[e] = bf2f(pb[k][e]) * rZ;
      o1[e] = bf2f(pb[k][4 + e]) * rZ;
    }
    *reinterpret_cast<f32x4*>(&arow[c0]) = o0;
    *reinterpret_cast<f32x4*>(&arow[c0 + 4]) = o1;
  }
  if (tid == 0) {
    float s = 0.f;
#pragma unroll
    for (int i = 0; i < 16; ++i) s += rowv[i];
    partial[bh * 64 + blockIdx.x] = s;
    if (h == 0) {
      float c = 0.f;
#pragma unroll
      for (int i = 0; i < 16; ++i) c += rowc[i];
      partial2[b * 64 + blockIdx.x] = c - 16.0f;  // diag always 1 -> subtract
    }
  }

  // ---- phase 3: PV on unnormalized ev; scale by 1/Z in epilogue ----
  f32x4 acc = {0.f, 0.f, 0.f, 0.f};
  const short* vrow = &VbT[(long)(bh * DHD + wv * 16 + lr) << 10];
#pragma unroll 8
  for (int k0 = 0; k0 < 32; ++k0) {
    const bf16x8 a = *reinterpret_cast<const bf16x8*>(sp(S, lr, k0 * 32 + lk * 8));
    const bf16x8 bb = *reinterpret_cast<const bf16x8*>(&vrow[k0 * 32 + lk * 8]);
    acc = __builtin_amdgcn_mfma_f32_16x16x32_bf16(a, bb, acc, 0, 0, 0);
  }
#pragma unroll
  for (int i = 0; i < 4; ++i) {
    const int row = lk * 4 + i;
    const float o = acc[i] * rowscale[row];
    AVb[((long)((b << 10) + i0 + row) << 9) + h * DHD + wv * 16 + lr] = f2bf(o);
  }
}

// ---------------------------------------------------------------------------
// K4: out = av @ Wo.T + bo (f32 out). grid (64, 8).
// ---------------------------------------------------------------------------
__global__ __launch_bounds__(256) void k_outproj(const short* __restrict__ AVb,
                                                 const float* __restrict__ Wo,
                                                 const float* __restrict__ bo,
                                                 float* __restrict__ out) {
  __shared__ __align__(16) short As[64][40];
  __shared__ __align__(16) short Bs[64][40];
  const int tid = threadIdx.x;
  const int lane = tid & 63, wv = tid >> 6;
  const int m0 = blockIdx.x * 64, o0 = blockIdx.y * 64;
  const f32x4 zero4 = {0.f, 0.f, 0.f, 0.f};
  f32x4 acc[4] = {zero4, zero4, zero4, zero4};
  const int ar = tid >> 2, ac = (tid & 3) * 8;
  const int br2 = tid >> 3, bc4 = (tid & 7) * 4;

  for (int ks = 0; ks < 16; ++ks) {
    const int k0 = ks * 32;
    __syncthreads();
    *reinterpret_cast<bf16x8*>(&As[ar][ac]) =
        *reinterpret_cast<const bf16x8*>(&AVb[((long)(m0 + ar) << 9) + k0 + ac]);
#pragma unroll
    for (int t = 0; t < 2; ++t) {
      const int rr = br2 + t * 32;
      const f32x4 vb = *reinterpret_cast<const f32x4*>(&Wo[(o0 + rr) * DIMD + k0 + bc4]);
      bf16x4 pbv;
#pragma unroll
      for (int i2 = 0; i2 < 4; ++i2) pbv[i2] = f2bf(vb[i2]);
      *reinterpret_cast<bf16x4*>(&Bs[rr][bc4]) = pbv;
    }
    __syncthreads();
    const int kk = (lane >> 4) * 8;
    const bf16x8 a = *reinterpret_cast<const bf16x8*>(&As[wv * 16 + (lane & 15)][kk]);
#pragma unroll
    for (int n = 0; n < 4; ++n) {
      const bf16x8 b = *reinterpret_cast<const bf16x8*>(&Bs[n * 16 + (lane & 15)][kk]);
      acc[n] = __builtin_amdgcn_mfma_f32_16x16x32_bf16(a, b, acc[n], 0, 0, 0);
    }
  }
  const int rbase = m0 + wv * 16 + ((lane >> 4) << 2);
#pragma unroll
  for (int i = 0; i < 4; ++i) {
#pragma unroll
    for (int n = 0; n < 4; ++n) {
      const int o = o0 + n * 16 + (lane & 15);
      out[((long)(rbase + i) << 9) + o] = acc[n][i] + bo[o];
    }
  }
}

// ---------------------------------------------------------------------------
// K5: finalize dcl: reduce 2048 clustering partials + 256 regular partials
// ---------------------------------------------------------------------------
__global__ __launch_bounds__(256) void k_finalize(const float* __restrict__ partial,
                                                  const float* __restrict__ partial2,
                                                  float* __restrict__ dcl) {
  const int tid = threadIdx.x;
  float s = 0.f;
#pragma unroll
  for (int t = 0; t < 8; ++t) s += partial[tid + t * 256];
  float s2 = partial2[tid];
  s = wave_sum(s);
  s2 = wave_sum(s2);
  __shared__ float red[4], red2[4];
  if ((tid & 63) == 0) { red[tid >> 6] = s; red2[tid >> 6] = s2; }
  __syncthreads();
  if (tid == 0) {
    const float cl = red[0] + red[1] + red[2] + red[3];
    const float rg = red2[0] + red2[1] + red2[2] + red2[3];
    *dcl = cl / (float)(NB * NH * NN) + KREG * rg / ((float)NN * (float)(NN - 1)) / (float)NB;
  }
}

extern "C" void kernel_launch(void* const* d_in, const int* in_sizes, int n_in,
                              void* d_out, int out_size, void* d_ws, size_t ws_size,
                              hipStream_t stream) {
  const float* x = (const float*)d_in[0];
  const float* mask = (const float*)d_in[1];
  const float* Wq = (const float*)d_in[2];
  const float* bq = (const float*)d_in[3];
  const float* Wk = (const float*)d_in[4];
  const float* bk = (const float*)d_in[5];
  const float* Wv = (const float*)d_in[6];
  const float* bv = (const float*)d_in[7];
  const float* Wo = (const float*)d_in[8];
  const float* bo = (const float*)d_in[9];

  float* out = (float*)d_out;
  float* attn = out + (size_t)NB * NN * DIMD;
  float* dcl = attn + (size_t)NB * NH * NN * NN;

  char* ws = (char*)d_ws;
  short* Qb = (short*)(ws);
  short* Kb = (short*)(ws + ((size_t)4 << 20));
  short* Vb = (short*)(ws + ((size_t)8 << 20));
  short* VbT = (short*)(ws + ((size_t)12 << 20));
  short* AVb = (short*)(ws + ((size_t)16 << 20));
  float* qn = (float*)(ws + ((size_t)20 << 20));
  float* kn = (float*)(ws + ((size_t)20 << 20) + (1 << 18));
  float* kms = (float*)(ws + ((size_t)20 << 20) + (2 << 18));       // 32 f32
  float* partial = (float*)(ws + ((size_t)20 << 20) + (3 << 18));   // 2048 f32
  float* partial2 = (float*)(ws + ((size_t)20 << 20) + (4 << 18));  // 256 f32

  k_qkv<<<dim3(64, 24), 256, 0, stream>>>(x, Wq, bq, Wk, bk, Wv, bv, Qb, Kb, Vb, qn, kn);
  k_vtrans<<<dim3(16, 32), 256, 0, stream>>>(Vb, VbT);
  k_kmax<<<dim3(32), 256, 0, stream>>>(kn, kms);
  k_attn<<<dim3(64, 32), 256, 0, stream>>>(Qb, Kb, VbT, mask, qn, kn, kms, attn, AVb,
                                           partial, partial2);
  k_outproj<<<dim3(64, 8), 256, 0, stream>>>(AVb, Wo, bo, out);
  k_finalize<<<1, 256, 0, stream>>>(partial, partial2, dcl);
}